// Round 9
// baseline (414.914 us; speedup 1.0000x reference)
//
#include <hip/hip_runtime.h>
#include <cstdint>

#define BB 256
#define SS 2048
#define TT 64
#define LOG64 4.158883083359672

// ---------------- new-path ws layout (float offsets) ----------------
#define OUTB 0
#define GBASE 256
#define LBASE 512
#define LSIZE (256 * 8 * 64)            // per-column log scales (max nseg=8)
#define PBASE_F (LBASE + LSIZE)         // 131584 floats
// P stored as bf16 (u16): (BB*nseg) matrices x 4096 entries

// ---------------- old-path (R7 fallback) constants ----------------
#define M_SPLIT 1024
#define WS_STRIDE 144

typedef short  s16x4  __attribute__((ext_vector_type(4)));
typedef float  f32x4v __attribute__((ext_vector_type(4)));
typedef unsigned int u32x2 __attribute__((ext_vector_type(2)));

__device__ __forceinline__ int ldtag(const uint32_t* tw, int i, int is64) {
    return (int)tw[i << is64];
}

// pack two f32 -> u32 of 2 bf16 (lo in low half), single instruction
__device__ __forceinline__ unsigned cvt_pk_bf16(float lo, float hi) {
    unsigned r;
    asm("v_cvt_pk_bf16_f32 %0, %1, %2" : "=v"(r) : "v"(lo), "v"(hi));
    return r;
}

// 16x16x16 bf16 MFMA: builtin if present, else raw asm (instruction is in gfx950 ISA)
__device__ __forceinline__ f32x4v mfma16(u32x2 a, u32x2 b, f32x4v c) {
#if __has_builtin(__builtin_amdgcn_mfma_f32_16x16x16bf16_1k)
    return __builtin_amdgcn_mfma_f32_16x16x16bf16_1k(
        __builtin_bit_cast(s16x4, a), __builtin_bit_cast(s16x4, b), c, 0, 0, 0);
#else
    f32x4v d;
    asm("v_mfma_f32_16x16x16_bf16 %0, %1, %2, %3"
        : "=v"(d) : "v"(a), "v"(b), "v"(c));
    return d;
#endif
}

// ================= segment matrix-product kernel =================
// grid = (BB*nseg, 4 strips); 1 wave/block. Strip w evolves cols [16w,16w+16)
// of P_s = M_t1 ... M_t0,  M_t = D_{exp(em_t)} E^T,  E = exp(trans)/64.
// 16x16x16 layouts: A row=l&15,k=(l>>4)*4+e; B col=l&15,k=(l>>4)*4+e;
// C col=l&15,row=(l>>4)*4+r  ->  C feeds next B with ZERO cross-lane movement.
__global__ __launch_bounds__(64, 4) void crf_seg_kernel(
    const float* __restrict__ em, const float* __restrict__ trans,
    float* __restrict__ ws, int sshift)
{
    const int l = threadIdx.x;
    const int nseg = 1 << sshift;
    const int b = blockIdx.x >> sshift;
    const int s = blockIdx.x & (nseg - 1);
    const int w = blockIdx.y;
    const int l15 = l & 15, l4 = l >> 4;
    __shared__ __align__(16) float f_lds[TT];

    // A[m][k] = E^T[m][k] = exp(trans[k][m])/64 ; m = mt*16+l15, k = kb*16+l4*4+e
#define EV(mt,kb,e) (__expf(trans[((kb)*16 + l4*4 + (e))*64 + (mt)*16 + l15]) * 0.015625f)
#define MKA(NM,mt,kb) u32x2 NM; NM[0]=cvt_pk_bf16(EV(mt,kb,0),EV(mt,kb,1)); \
                      NM[1]=cvt_pk_bf16(EV(mt,kb,2),EV(mt,kb,3));
    MKA(A00,0,0) MKA(A01,0,1) MKA(A02,0,2) MKA(A03,0,3)
    MKA(A10,1,0) MKA(A11,1,1) MKA(A12,1,2) MKA(A13,1,3)
    MKA(A20,2,0) MKA(A21,2,1) MKA(A22,2,2) MKA(A23,2,3)
    MKA(A30,3,0) MKA(A31,3,1) MKA(A32,3,2) MKA(A33,3,3)
#undef MKA
#undef EV

    // B init: identity strip (col cn)
    const int cn = w * 16 + l15;
    u32x2 B0u, B1u, B2u, B3u;
#define BINIT(Bu,kb) { float v0=((kb)*16+l4*4+0)==cn?1.f:0.f; \
                       float v1=((kb)*16+l4*4+1)==cn?1.f:0.f; \
                       float v2=((kb)*16+l4*4+2)==cn?1.f:0.f; \
                       float v3=((kb)*16+l4*4+3)==cn?1.f:0.f; \
                       Bu[0]=cvt_pk_bf16(v0,v1); Bu[1]=cvt_pk_bf16(v2,v3); }
    BINIT(B0u,0) BINIT(B1u,1) BINIT(B2u,2) BINIT(B3u,3)
#undef BINIT

    const size_t ebase = (size_t)b * (SS * TT);
    const int L  = SS >> sshift;
    const int t0 = s * L + 1;
    const int t1 = (s == nseg - 1) ? (SS - 1) : (s + 1) * L;
    const int nst = t1 - t0 + 1;

    float p0 = em[ebase + (size_t)(t0 + 0) * TT + l];
    float p1 = em[ebase + (size_t)(t0 + 1) * TT + l];
    float p2 = em[ebase + (size_t)(t0 + 2) * TT + l];
    float p3 = em[ebase + (size_t)(t0 + 3) * TT + l];

    float logacc = 0.f;                          // per-COLUMN log scale (cols indep.)
    const f32x4v Zf = {0.f, 0.f, 0.f, 0.f};
    f32x4v C0, C1, C2, C3;

    for (int si = 0; si < nst; ++si) {
        const float fr = __expf(p0);
        p0 = p1; p1 = p2; p2 = p3;
        int tp = t0 + si + 4; if (tp > SS - 1) tp = SS - 1;
        p3 = em[ebase + (size_t)tp * TT + l];

        f_lds[l] = fr;                           // f_t by state; same-wave in-order DS

        C0 = mfma16(A00,B0u,Zf); C0 = mfma16(A01,B1u,C0); C0 = mfma16(A02,B2u,C0); C0 = mfma16(A03,B3u,C0);
        C1 = mfma16(A10,B0u,Zf); C1 = mfma16(A11,B1u,C1); C1 = mfma16(A12,B2u,C1); C1 = mfma16(A13,B3u,C1);
        C2 = mfma16(A20,B0u,Zf); C2 = mfma16(A21,B1u,C2); C2 = mfma16(A22,B2u,C2); C2 = mfma16(A23,B3u,C2);
        C3 = mfma16(A30,B0u,Zf); C3 = mfma16(A31,B1u,C3); C3 = mfma16(A32,B2u,C3); C3 = mfma16(A33,B3u,C3);

        // row scale by f_t[m]; m = mt*16 + l4*4 + r (broadcast f32x4 from LDS)
        C0 *= *(const f32x4v*)(f_lds +  0 + l4 * 4);
        C1 *= *(const f32x4v*)(f_lds + 16 + l4 * 4);
        C2 *= *(const f32x4v*)(f_lds + 32 + l4 * 4);
        C3 *= *(const f32x4v*)(f_lds + 48 + l4 * 4);

        // per-column renorm (cols evolve independently): max over the 4 lanes
        // sharing col l15 (xor16 + xor32), exact per-column log bookkeeping
        if ((si & 7) == 7) {
            float mx = fmaxf(fmaxf(fmaxf(C0[0],C0[1]),fmaxf(C0[2],C0[3])),
                       fmaxf(fmaxf(fmaxf(C1[0],C1[1]),fmaxf(C1[2],C1[3])),
                       fmaxf(fmaxf(fmaxf(C2[0],C2[1]),fmaxf(C2[2],C2[3])),
                             fmaxf(fmaxf(C3[0],C3[1]),fmaxf(C3[2],C3[3])))));
            mx = fmaxf(mx, __shfl_xor(mx, 16));
            mx = fmaxf(mx, __shfl_xor(mx, 32));
            const float inv = __builtin_amdgcn_rcpf(mx);
            C0 *= inv; C1 *= inv; C2 *= inv; C3 *= inv;
            logacc += __logf(mx);
        }

        // C -> next B (same lane, same k-slot): pack to bf16
        B0u[0] = cvt_pk_bf16(C0[0],C0[1]); B0u[1] = cvt_pk_bf16(C0[2],C0[3]);
        B1u[0] = cvt_pk_bf16(C1[0],C1[1]); B1u[1] = cvt_pk_bf16(C1[2],C1[3]);
        B2u[0] = cvt_pk_bf16(C2[0],C2[1]); B2u[1] = cvt_pk_bf16(C2[2],C2[3]);
        B3u[0] = cvt_pk_bf16(C3[0],C3[1]); B3u[1] = cvt_pk_bf16(C3[2],C3[3]);
    }

    // store P^T[col=cn][m] as bf16
    uint16_t* ptu = (uint16_t*)(ws + PBASE_F)
                  + (size_t)blockIdx.x * 4096 + (size_t)cn * 64 + l4 * 4;
    *(unsigned*)(ptu +  0) = cvt_pk_bf16(C0[0],C0[1]);
    *(unsigned*)(ptu +  2) = cvt_pk_bf16(C0[2],C0[3]);
    *(unsigned*)(ptu + 16) = cvt_pk_bf16(C1[0],C1[1]);
    *(unsigned*)(ptu + 18) = cvt_pk_bf16(C1[2],C1[3]);
    *(unsigned*)(ptu + 32) = cvt_pk_bf16(C2[0],C2[1]);
    *(unsigned*)(ptu + 34) = cvt_pk_bf16(C2[2],C2[3]);
    *(unsigned*)(ptu + 48) = cvt_pk_bf16(C3[0],C3[1]);
    *(unsigned*)(ptu + 50) = cvt_pk_bf16(C3[2],C3[3]);
    if (l4 == 0)
        ws[LBASE + blockIdx.x * 64 + cn] = logacc + (float)((double)nst * LOG64);
}

// ================= combine: alpha <- P_s alpha over segments =================
__global__ __launch_bounds__(64) void crf_combine2(
    const float* __restrict__ em, float* __restrict__ ws, int sshift)
{
    const int b = blockIdx.x, m = threadIdx.x;
    const int nseg = 1 << sshift;
    __shared__ float xs[TT];
    float alpha = __expf(em[(size_t)b * (SS * TT) + m]);   // alpha_0
    float logA = 0.f;
    for (int s = 0; s < nseg; ++s) {
        const int seg = b * nseg + s;
        const float Li = ws[LBASE + seg * 64 + m];         // per-column scale
        float Lmax = Li;
        for (int off = 1; off < 64; off <<= 1) Lmax = fmaxf(Lmax, __shfl_xor(Lmax, off));
        xs[m] = alpha * __expf(Li - Lmax);                 // same-wave in-order DS
        const uint16_t* Pp = (const uint16_t*)(ws + PBASE_F) + (size_t)seg * 4096;
        float y = 0.f;
#pragma unroll 8
        for (int i = 0; i < TT; ++i) {
            const float pv = __uint_as_float((unsigned)Pp[i * 64 + m] << 16);
            y = fmaf(pv, xs[i], y);                        // coalesced bf16 rows
        }
        logA += Lmax;
        float mx = y;
        for (int off = 1; off < 64; off <<= 1) mx = fmaxf(mx, __shfl_xor(mx, off));
        alpha = y * __builtin_amdgcn_rcpf(mx);
        logA += __logf(mx);
    }
    float ssum = alpha;
    for (int off = 1; off < 64; off <<= 1) ssum += __shfl_xor(ssum, off);
    if (m == 0)
        ws[OUTB + b] = ws[GBASE + b] - (logA + __logf(ssum));   // gold - logZ
}

// ================= gold score (shared by both paths) =================
__global__ __launch_bounds__(256) void crf_gold_kernel(
    const float* __restrict__ em, const float* __restrict__ trans,
    const uint32_t* __restrict__ tw, float* __restrict__ gdst, int gstride)
{
    const int b = blockIdx.x, tid = threadIdx.x;
    uint32_t orv = 0;
    for (int k = 1; k < 32; k += 2) orv |= tw[k];
    const int is64 = (orv == 0) ? 1 : 0;
    const int    tbase = b * SS;
    const size_t ebase = (size_t)b * SS * TT;
    float s = 0.0f;
    for (int t = tid; t < SS; t += 256) {
        const int tg = ldtag(tw, tbase + t, is64);
        float v = em[ebase + (size_t)t * TT + tg];
        if (t > 0) {
            const int tp = ldtag(tw, tbase + t - 1, is64);
            v += trans[tp * TT + tg];
        }
        s += v;
    }
    for (int off = 1; off < 64; off <<= 1) s += __shfl_xor(s, off);
    __shared__ float sh[4];
    if ((tid & 63) == 0) sh[tid >> 6] = s;
    __syncthreads();
    if (tid == 0) gdst[b * gstride] = sh[0] + sh[1] + sh[2] + sh[3];
}

// ================= old path (R7, proven fallback) =================
__device__ __forceinline__ float qsum4(float v) {
    int a = __builtin_amdgcn_mov_dpp(__float_as_int(v), 0xB1, 0xF, 0xF, true);
    float v1 = v + __int_as_float(a);
    int b2 = __builtin_amdgcn_mov_dpp(__float_as_int(v1), 0x4E, 0xF, 0xF, true);
    return v1 + __int_as_float(b2);
}
#define LDS_BARRIER() asm volatile("s_waitcnt lgkmcnt(0)\n\ts_barrier" ::: "memory")

template <int DIR>
__device__ __forceinline__ void fb_run(const float* __restrict__ em,
                                       const float* __restrict__ trans,
                                       float* __restrict__ ws,
                                       float* __restrict__ qbuf,
                                       int b, int tid)
{
    const int l   = tid & 63;
    const int w   = tid >> 6;
    const int j   = (w << 4) | (l >> 2);
    const int sub = l & 3;
#define TRIDX(k) (DIR ? (j * 64 + (sub * 16 + (k))) : ((sub * 16 + (k)) * 64 + j))
#define ED(k) const float E##k = __expf(trans[TRIDX(k)]) * 0.015625f;
    ED(0) ED(1) ED(2) ED(3) ED(4) ED(5) ED(6) ED(7)
    ED(8) ED(9) ED(10) ED(11) ED(12) ED(13) ED(14) ED(15)
#undef ED
#undef TRIDX
    const size_t ebase  = (size_t)b * SS * TT;
    constexpr int nsteps = DIR ? (SS - M_SPLIT) : (M_SPLIT - 1);
    constexpr int estep  = DIR ? -TT : TT;
    constexpr int t0     = DIR ? (SS - 2) : 1;
    const float* ep = em + ebase + (size_t)t0 * TT + j;
    float p0 = ep[0];
    float p1 = ep[1 * estep];
    float p2 = ep[2 * estep];
    float p3 = ep[3 * estep];
    if (tid < TT) {
        const size_t it = DIR ? ((size_t)(SS - 1) * TT) : 0;
        qbuf[tid] = __expf(em[ebase + it + tid]);
    }
    LDS_BARRIER();
    float logsum = 0.0f;
    int cur = 0;
    for (int si = 0; si < nsteps; ++si) {
        const float e = p0;
        p0 = p1; p1 = p2; p2 = p3;
        p3 = ep[4 * estep];
        ep += estep;
        float* rb = qbuf + (cur << 6);
        float* wb = qbuf + ((cur ^ 1) << 6);
        const float4 q0 = *(const float4*)(rb + sub * 16 + 0);
        const float4 q1 = *(const float4*)(rb + sub * 16 + 4);
        const float4 q2 = *(const float4*)(rb + sub * 16 + 8);
        const float4 q3 = *(const float4*)(rb + sub * 16 + 12);
        float a0 = 0, a1 = 0, a2 = 0, a3 = 0;
        a0 = fmaf(q0.x, E0,  a0); a1 = fmaf(q0.y, E1,  a1);
        a2 = fmaf(q0.z, E2,  a2); a3 = fmaf(q0.w, E3,  a3);
        a0 = fmaf(q1.x, E4,  a0); a1 = fmaf(q1.y, E5,  a1);
        a2 = fmaf(q1.z, E6,  a2); a3 = fmaf(q1.w, E7,  a3);
        a0 = fmaf(q2.x, E8,  a0); a1 = fmaf(q2.y, E9,  a1);
        a2 = fmaf(q2.z, E10, a2); a3 = fmaf(q2.w, E11, a3);
        a0 = fmaf(q3.x, E12, a0); a1 = fmaf(q3.y, E13, a1);
        a2 = fmaf(q3.z, E14, a2); a3 = fmaf(q3.w, E15, a3);
        float dot = (a0 + a1) + (a2 + a3);
        dot = qsum4(dot);
        float fv = __expf(e);
        if (DIR && si == nsteps - 1) fv = 1.0f;
        float wval = dot * fv;
        if ((si & 63) == 63) {
            const float m = rb[0];
            wval *= __builtin_amdgcn_rcpf(m);
            if (tid == 0) logsum += __logf(m);
        }
        if (sub == 0) wb[j] = wval;
        LDS_BARRIER();
        cur ^= 1;
    }
    const float* fin = qbuf + (cur << 6);
    float* wsb = ws + (size_t)b * WS_STRIDE;
    if (tid < TT) wsb[(DIR ? TT : 0) + tid] = fin[tid];
    if (tid == 0) wsb[DIR ? 129 : 128] = (float)((double)nsteps * LOG64) + logsum;
}

__global__ __launch_bounds__(256) void crf_fb_kernel(
    const float* __restrict__ em, const float* __restrict__ trans,
    float* __restrict__ ws)
{
    const int b   = blockIdx.x & (BB - 1);
    const int dir = blockIdx.x >> 8;
    __shared__ __align__(16) float qbuf[2 * TT];
    if (dir == 0) fb_run<0>(em, trans, ws, qbuf, b, threadIdx.x);
    else          fb_run<1>(em, trans, ws, qbuf, b, threadIdx.x);
}

__global__ __launch_bounds__(64) void crf_combine_kernel(
    const float* __restrict__ ws, float* __restrict__ outb)
{
    const int b = blockIdx.x, lane = threadIdx.x;
    const float* wsb = ws + (size_t)b * WS_STRIDE;
    float p = wsb[lane] * wsb[64 + lane];
    for (int off = 1; off < 64; off <<= 1) p += __shfl_xor(p, off);
    if (lane == 0) {
        const float logz = wsb[128] + wsb[129] + __logf(p);
        outb[b] = wsb[130] - logz;
    }
}

__global__ __launch_bounds__(256) void crf_final_kernel(
    const float* __restrict__ vals, float* __restrict__ out)
{
    const int l = threadIdx.x;
    float v = vals[l];
    for (int off = 1; off < 64; off <<= 1) v += __shfl_xor(v, off);
    __shared__ float sh[4];
    if ((l & 63) == 0) sh[l >> 6] = v;
    __syncthreads();
    if (l == 0) out[0] = -(sh[0] + sh[1] + sh[2] + sh[3]) * (1.0f / BB);
}

extern "C" void kernel_launch(void* const* d_in, const int* in_sizes, int n_in,
                              void* d_out, int out_size, void* d_ws, size_t ws_size,
                              hipStream_t stream) {
    const float*    em    = (const float*)d_in[0];
    const float*    trans = (const float*)d_in[1];
    const uint32_t* tw    = (const uint32_t*)d_in[2];
    float* ws = (float*)d_ws;

    // adaptive segment count by workspace: 8 -> ~17.3MB, 4 -> ~8.9MB, 2 -> ~4.7MB
    int sshift = 0;
    const size_t hdr = (size_t)PBASE_F * 4;
    if      (ws_size >= hdr + (((size_t)BB << 3) * 4096 * 2)) sshift = 3;
    else if (ws_size >= hdr + (((size_t)BB << 2) * 4096 * 2)) sshift = 2;
    else if (ws_size >= hdr + (((size_t)BB << 1) * 4096 * 2)) sshift = 1;

    if (sshift) {
        dim3 g(BB << sshift, 4);
        crf_seg_kernel<<<g, 64, 0, stream>>>(em, trans, ws, sshift);
        crf_gold_kernel<<<BB, 256, 0, stream>>>(em, trans, tw, ws + GBASE, 1);
        crf_combine2<<<BB, 64, 0, stream>>>(em, ws, sshift);
        crf_final_kernel<<<1, 256, 0, stream>>>(ws + OUTB, (float*)d_out);
        return;
    }

    // fallback: proven R7 path
    float* outb = ws + (size_t)BB * WS_STRIDE;
    crf_fb_kernel<<<2 * BB, 256, 0, stream>>>(em, trans, ws);
    crf_gold_kernel<<<BB, 256, 0, stream>>>(em, trans, tw, ws + 130, WS_STRIDE);
    crf_combine_kernel<<<BB, 64, 0, stream>>>(ws, outb);
    crf_final_kernel<<<1, 256, 0, stream>>>(outb, (float*)d_out);
}

// Round 11
// 294.531 us; speedup vs baseline: 1.4087x; 1.4087x over previous
//
#include <hip/hip_runtime.h>
#include <cstdint>

#define BB 256
#define SS 2048
#define TT 64
#define LOG64 4.158883083359672

// ---------------- ws layout (float offsets) ----------------
#define OUTB 0
#define GBASE 256
#define LBASE 512
#define LSIZE (256 * 8 * 64)
#define PBASE_F (LBASE + LSIZE)
// P stored as bf16: (BB*nseg) matrices x 4096 entries

// ---------------- old-path (R7 fallback) constants ----------------
#define M_SPLIT 1024
#define WS_STRIDE 144

typedef float  f32x16 __attribute__((ext_vector_type(16)));
typedef float  f32x4v __attribute__((ext_vector_type(4)));
typedef unsigned int u32x4 __attribute__((ext_vector_type(4)));
typedef unsigned int u32x2 __attribute__((ext_vector_type(2)));
typedef short  s16x4  __attribute__((ext_vector_type(4)));

__device__ __forceinline__ int ldtag(const uint32_t* tw, int i, int is64) {
    return (int)tw[i << is64];
}

__device__ __forceinline__ unsigned cvt_pk_bf16(float lo, float hi) {
    unsigned r;
    asm("v_cvt_pk_bf16_f32 %0, %1, %2" : "=v"(r) : "v"(lo), "v"(hi));
    return r;
}

// exchange x.lanes[32:64] with y.lanes[0:32]
#define PLSWAP(x, y) asm("v_permlane32_swap_b32 %0, %1" : "+v"(x), "+v"(y))

#if __has_builtin(__builtin_amdgcn_mfma_f32_32x32x16_bf16)
#define HAVE32 1
typedef __bf16 bf16x8 __attribute__((ext_vector_type(8)));
__device__ __forceinline__ f32x16 mfma32(u32x4 a, u32x4 b, f32x16 c) {
    // builtin (NOT raw asm): compiler must see the MFMA def to insert the
    // mandatory MFMA->VALU hazard wait-states (R10's all-asm MFMA skipped them
    // -> stale accumulator reads -> absmax 256).
    return __builtin_amdgcn_mfma_f32_32x32x16_bf16(
        __builtin_bit_cast(bf16x8, a), __builtin_bit_cast(bf16x8, b), c, 0, 0, 0);
}
#else
#define HAVE32 0
#endif

#if __has_builtin(__builtin_amdgcn_mfma_f32_16x16x16bf16_1k)
#define HAVE16 1
__device__ __forceinline__ f32x4v mfma16(u32x2 a, u32x2 b, f32x4v c) {
    return __builtin_amdgcn_mfma_f32_16x16x16bf16_1k(
        __builtin_bit_cast(s16x4, a), __builtin_bit_cast(s16x4, b), c, 0, 0, 0);
}
#else
#define HAVE16 0
#endif

#if HAVE32
// ================= segment matrix-product kernel (32x32x16) =================
// grid = (BB*nseg, 2 strips); 1 wave/block. Strip w evolves cols [32w,32w+32)
// of P_s = M_t1 ... M_t0,  M_t = D_{exp(em_t)} E^T,  E = exp(trans)/64.
// Layouts (32x32x16 bf16): A row=l&31,k=(l>>5)*8+e ; B col=l&31,k=(l>>5)*8+e ;
// C col=l&31,row=(r&3)+8*(r>>2)+4*(l>>5)  [HW-verified m74/m101].
// C->B feed: cvt_pk pairs + v_permlane32_swap (each swap's BOTH outputs are B words).
__global__ __launch_bounds__(64, 3) void crf_seg32_kernel(
    const float* __restrict__ em, const float* __restrict__ trans,
    float* __restrict__ ws, int sshift)
{
    const int l = threadIdx.x;
    const int c = l & 31, h = l >> 5;
    const int b = blockIdx.x >> sshift;
    const int s = blockIdx.x & ((1 << sshift) - 1);
    const int w = blockIdx.y;
    const int cn = w * 32 + c;                 // global column of this lane
    __shared__ __align__(16) float f_lds[TT];

    const f32x16 ZZ = {0,0,0,0,0,0,0,0,0,0,0,0,0,0,0,0};

    // A tiles (E^T): A[m][k], m = 32mt + c, k = 16kt + 8h + e
#define MKA(NM, mt, kt) u32x4 NM; { \
        const int kb = 16*(kt) + 8*h; const int mc = 32*(mt) + c; \
        const float e0 = __expf(trans[(kb+0)*64 + mc]) * 0.015625f; \
        const float e1 = __expf(trans[(kb+1)*64 + mc]) * 0.015625f; \
        const float e2 = __expf(trans[(kb+2)*64 + mc]) * 0.015625f; \
        const float e3 = __expf(trans[(kb+3)*64 + mc]) * 0.015625f; \
        const float e4 = __expf(trans[(kb+4)*64 + mc]) * 0.015625f; \
        const float e5 = __expf(trans[(kb+5)*64 + mc]) * 0.015625f; \
        const float e6 = __expf(trans[(kb+6)*64 + mc]) * 0.015625f; \
        const float e7 = __expf(trans[(kb+7)*64 + mc]) * 0.015625f; \
        NM[0] = cvt_pk_bf16(e0, e1); NM[1] = cvt_pk_bf16(e2, e3); \
        NM[2] = cvt_pk_bf16(e4, e5); NM[3] = cvt_pk_bf16(e6, e7); }
    MKA(A00, 0, 0) MKA(A01, 0, 1) MKA(A02, 0, 2) MKA(A03, 0, 3)
    MKA(A10, 1, 0) MKA(A11, 1, 1) MKA(A12, 1, 2) MKA(A13, 1, 3)
#undef MKA

    // B init: identity strip. B[k][cn] = (k == cn), k = 16kt + 8h + e
#define MKB(NM, kt) u32x4 NM; { \
        const int kb = 16*(kt) + 8*h; \
        NM[0] = cvt_pk_bf16(kb+0==cn?1.f:0.f, kb+1==cn?1.f:0.f); \
        NM[1] = cvt_pk_bf16(kb+2==cn?1.f:0.f, kb+3==cn?1.f:0.f); \
        NM[2] = cvt_pk_bf16(kb+4==cn?1.f:0.f, kb+5==cn?1.f:0.f); \
        NM[3] = cvt_pk_bf16(kb+6==cn?1.f:0.f, kb+7==cn?1.f:0.f); }
    MKB(B0, 0) MKB(B1, 1) MKB(B2, 2) MKB(B3, 3)
#undef MKB

    const size_t ebase = (size_t)b * (SS * TT);
    const int nseg = 1 << sshift;
    const int L  = SS >> sshift;
    const int t0 = s * L + 1;
    const int t1 = (s == nseg - 1) ? (SS - 1) : (s + 1) * L;
    const int nst = t1 - t0 + 1;

    float p0 = em[ebase + (size_t)(t0 + 0) * TT + l];
    float p1 = em[ebase + (size_t)(t0 + 1) * TT + l];
    float p2 = em[ebase + (size_t)(t0 + 2) * TT + l];
    float p3 = em[ebase + (size_t)(t0 + 3) * TT + l];

    float logacc = 0.f;
    f32x16 c0, c1;

    for (int si = 0; si < nst; ++si) {
        const float fr = __expf(p0);
        p0 = p1; p1 = p2; p2 = p3;
        int tp = t0 + si + 4; if (tp > SS - 1) tp = SS - 1;
        p3 = em[ebase + (size_t)tp * TT + l];

        f_lds[l] = fr;                         // same-wave in-order DS

        // ---- 8 MFMA: C(mt) = sum_kt A[mt][kt] * B[kt] ----
        c0 = mfma32(A00, B0, ZZ);  c1 = mfma32(A10, B0, ZZ);
        c0 = mfma32(A01, B1, c0);  c1 = mfma32(A11, B1, c1);
        c0 = mfma32(A02, B2, c0);  c1 = mfma32(A12, B2, c1);
        c0 = mfma32(A03, B3, c0);  c1 = mfma32(A13, B3, c1);

        // ---- row scale by f_t: reg r of tile mt -> row (r&3)+8*(r>>2)+4h+32mt ----
        const f32x4v f0 = *(const f32x4v*)(f_lds +  0 + 4*h);
        const f32x4v f1 = *(const f32x4v*)(f_lds +  8 + 4*h);
        const f32x4v f2 = *(const f32x4v*)(f_lds + 16 + 4*h);
        const f32x4v f3 = *(const f32x4v*)(f_lds + 24 + 4*h);
        const f32x4v f4 = *(const f32x4v*)(f_lds + 32 + 4*h);
        const f32x4v f5 = *(const f32x4v*)(f_lds + 40 + 4*h);
        const f32x4v f6 = *(const f32x4v*)(f_lds + 48 + 4*h);
        const f32x4v f7 = *(const f32x4v*)(f_lds + 56 + 4*h);
#define SC(C_, q, FV) { C_[4*(q)+0] *= FV[0]; C_[4*(q)+1] *= FV[1]; \
                        C_[4*(q)+2] *= FV[2]; C_[4*(q)+3] *= FV[3]; }
        SC(c0,0,f0) SC(c0,1,f1) SC(c0,2,f2) SC(c0,3,f3)
        SC(c1,0,f4) SC(c1,1,f5) SC(c1,2,f6) SC(c1,3,f7)
#undef SC

        // ---- per-column renorm every 8 steps (partner lane = l^32, same column) ----
        if ((si & 7) == 7) {
            float mx = c0[0];
#define MX(v) mx = fmaxf(mx, v);
            MX(c0[1]) MX(c0[2]) MX(c0[3]) MX(c0[4]) MX(c0[5]) MX(c0[6]) MX(c0[7])
            MX(c0[8]) MX(c0[9]) MX(c0[10]) MX(c0[11]) MX(c0[12]) MX(c0[13]) MX(c0[14]) MX(c0[15])
            MX(c1[0]) MX(c1[1]) MX(c1[2]) MX(c1[3]) MX(c1[4]) MX(c1[5]) MX(c1[6]) MX(c1[7])
            MX(c1[8]) MX(c1[9]) MX(c1[10]) MX(c1[11]) MX(c1[12]) MX(c1[13]) MX(c1[14]) MX(c1[15])
#undef MX
            mx = fmaxf(mx, __shfl_xor(mx, 32));
            const float inv = __builtin_amdgcn_rcpf(mx);
            c0 *= inv; c1 *= inv;
            logacc += __logf(mx);
        }

        // ---- C -> next B: pack reg pairs, permlane32_swap; both outputs are B words ----
        {
            unsigned q0 = cvt_pk_bf16(c0[0],  c0[1]);
            unsigned q1 = cvt_pk_bf16(c0[2],  c0[3]);
            unsigned q2 = cvt_pk_bf16(c0[4],  c0[5]);
            unsigned q3 = cvt_pk_bf16(c0[6],  c0[7]);
            PLSWAP(q0, q2); PLSWAP(q1, q3);
            B0[0]=q0; B0[1]=q1; B0[2]=q2; B0[3]=q3;
            unsigned q4 = cvt_pk_bf16(c0[8],  c0[9]);
            unsigned q5 = cvt_pk_bf16(c0[10], c0[11]);
            unsigned q6 = cvt_pk_bf16(c0[12], c0[13]);
            unsigned q7 = cvt_pk_bf16(c0[14], c0[15]);
            PLSWAP(q4, q6); PLSWAP(q5, q7);
            B1[0]=q4; B1[1]=q5; B1[2]=q6; B1[3]=q7;
            unsigned r0 = cvt_pk_bf16(c1[0],  c1[1]);
            unsigned r1 = cvt_pk_bf16(c1[2],  c1[3]);
            unsigned r2 = cvt_pk_bf16(c1[4],  c1[5]);
            unsigned r3 = cvt_pk_bf16(c1[6],  c1[7]);
            PLSWAP(r0, r2); PLSWAP(r1, r3);
            B2[0]=r0; B2[1]=r1; B2[2]=r2; B2[3]=r3;
            unsigned r4 = cvt_pk_bf16(c1[8],  c1[9]);
            unsigned r5 = cvt_pk_bf16(c1[10], c1[11]);
            unsigned r6 = cvt_pk_bf16(c1[12], c1[13]);
            unsigned r7 = cvt_pk_bf16(c1[14], c1[15]);
            PLSWAP(r4, r6); PLSWAP(r5, r7);
            B3[0]=r4; B3[1]=r5; B3[2]=r6; B3[3]=r7;
        }
    }

    // store P^T[cn][row] as bf16; rows: quad q of tile mt -> 32mt + 8q + 4h + {0..3}
    uint16_t* ptu = (uint16_t*)(ws + PBASE_F)
                  + (size_t)blockIdx.x * 4096 + (size_t)cn * 64;
#define STQ(C_, q, base) { \
        *(unsigned*)(ptu + (base) + 8*(q) + 4*h)     = cvt_pk_bf16(C_[4*(q)+0], C_[4*(q)+1]); \
        *(unsigned*)(ptu + (base) + 8*(q) + 4*h + 2) = cvt_pk_bf16(C_[4*(q)+2], C_[4*(q)+3]); }
    STQ(c0,0,0) STQ(c0,1,0) STQ(c0,2,0) STQ(c0,3,0)
    STQ(c1,0,32) STQ(c1,1,32) STQ(c1,2,32) STQ(c1,3,32)
#undef STQ
    if (h == 0)
        ws[LBASE + blockIdx.x * 64 + cn] = logacc + (float)((double)nst * LOG64);
}
#endif // HAVE32

#if HAVE16
// ================= R9-verified 16x16x16 segment kernel (fallback) =================
__global__ __launch_bounds__(64, 4) void crf_seg_kernel(
    const float* __restrict__ em, const float* __restrict__ trans,
    float* __restrict__ ws, int sshift)
{
    const int l = threadIdx.x;
    const int nseg = 1 << sshift;
    const int b = blockIdx.x >> sshift;
    const int s = blockIdx.x & (nseg - 1);
    const int w = blockIdx.y;
    const int l15 = l & 15, l4 = l >> 4;
    __shared__ __align__(16) float f_lds[TT];

#define EV(mt,kb,e) (__expf(trans[((kb)*16 + l4*4 + (e))*64 + (mt)*16 + l15]) * 0.015625f)
#define MKA(NM,mt,kb) u32x2 NM; NM[0]=cvt_pk_bf16(EV(mt,kb,0),EV(mt,kb,1)); \
                      NM[1]=cvt_pk_bf16(EV(mt,kb,2),EV(mt,kb,3));
    MKA(A00,0,0) MKA(A01,0,1) MKA(A02,0,2) MKA(A03,0,3)
    MKA(A10,1,0) MKA(A11,1,1) MKA(A12,1,2) MKA(A13,1,3)
    MKA(A20,2,0) MKA(A21,2,1) MKA(A22,2,2) MKA(A23,2,3)
    MKA(A30,3,0) MKA(A31,3,1) MKA(A32,3,2) MKA(A33,3,3)
#undef MKA
#undef EV

    const int cn = w * 16 + l15;
    u32x2 B0u, B1u, B2u, B3u;
#define BINIT(Bu,kb) { float v0=((kb)*16+l4*4+0)==cn?1.f:0.f; \
                       float v1=((kb)*16+l4*4+1)==cn?1.f:0.f; \
                       float v2=((kb)*16+l4*4+2)==cn?1.f:0.f; \
                       float v3=((kb)*16+l4*4+3)==cn?1.f:0.f; \
                       Bu[0]=cvt_pk_bf16(v0,v1); Bu[1]=cvt_pk_bf16(v2,v3); }
    BINIT(B0u,0) BINIT(B1u,1) BINIT(B2u,2) BINIT(B3u,3)
#undef BINIT

    const size_t ebase = (size_t)b * (SS * TT);
    const int L  = SS >> sshift;
    const int t0 = s * L + 1;
    const int t1 = (s == nseg - 1) ? (SS - 1) : (s + 1) * L;
    const int nst = t1 - t0 + 1;

    float p0 = em[ebase + (size_t)(t0 + 0) * TT + l];
    float p1 = em[ebase + (size_t)(t0 + 1) * TT + l];
    float p2 = em[ebase + (size_t)(t0 + 2) * TT + l];
    float p3 = em[ebase + (size_t)(t0 + 3) * TT + l];

    float logacc = 0.f;
    const f32x4v Zf = {0.f, 0.f, 0.f, 0.f};
    f32x4v C0, C1, C2, C3;

    for (int si = 0; si < nst; ++si) {
        const float fr = __expf(p0);
        p0 = p1; p1 = p2; p2 = p3;
        int tp = t0 + si + 4; if (tp > SS - 1) tp = SS - 1;
        p3 = em[ebase + (size_t)tp * TT + l];

        f_lds[l] = fr;

        C0 = mfma16(A00,B0u,Zf); C0 = mfma16(A01,B1u,C0); C0 = mfma16(A02,B2u,C0); C0 = mfma16(A03,B3u,C0);
        C1 = mfma16(A10,B0u,Zf); C1 = mfma16(A11,B1u,C1); C1 = mfma16(A12,B2u,C1); C1 = mfma16(A13,B3u,C1);
        C2 = mfma16(A20,B0u,Zf); C2 = mfma16(A21,B1u,C2); C2 = mfma16(A22,B2u,C2); C2 = mfma16(A23,B3u,C2);
        C3 = mfma16(A30,B0u,Zf); C3 = mfma16(A31,B1u,C3); C3 = mfma16(A32,B2u,C3); C3 = mfma16(A33,B3u,C3);

        C0 *= *(const f32x4v*)(f_lds +  0 + l4 * 4);
        C1 *= *(const f32x4v*)(f_lds + 16 + l4 * 4);
        C2 *= *(const f32x4v*)(f_lds + 32 + l4 * 4);
        C3 *= *(const f32x4v*)(f_lds + 48 + l4 * 4);

        if ((si & 7) == 7) {
            float mx = fmaxf(fmaxf(fmaxf(C0[0],C0[1]),fmaxf(C0[2],C0[3])),
                       fmaxf(fmaxf(fmaxf(C1[0],C1[1]),fmaxf(C1[2],C1[3])),
                       fmaxf(fmaxf(fmaxf(C2[0],C2[1]),fmaxf(C2[2],C2[3])),
                             fmaxf(fmaxf(C3[0],C3[1]),fmaxf(C3[2],C3[3])))));
            mx = fmaxf(mx, __shfl_xor(mx, 16));
            mx = fmaxf(mx, __shfl_xor(mx, 32));
            const float inv = __builtin_amdgcn_rcpf(mx);
            C0 *= inv; C1 *= inv; C2 *= inv; C3 *= inv;
            logacc += __logf(mx);
        }

        B0u[0] = cvt_pk_bf16(C0[0],C0[1]); B0u[1] = cvt_pk_bf16(C0[2],C0[3]);
        B1u[0] = cvt_pk_bf16(C1[0],C1[1]); B1u[1] = cvt_pk_bf16(C1[2],C1[3]);
        B2u[0] = cvt_pk_bf16(C2[0],C2[1]); B2u[1] = cvt_pk_bf16(C2[2],C2[3]);
        B3u[0] = cvt_pk_bf16(C3[0],C3[1]); B3u[1] = cvt_pk_bf16(C3[2],C3[3]);
    }

    uint16_t* ptu = (uint16_t*)(ws + PBASE_F)
                  + (size_t)(blockIdx.x * 4 + w) * 0 // placeholder, real index below
                  ;
    (void)ptu;
    uint16_t* pt2 = (uint16_t*)(ws + PBASE_F)
                  + (size_t)blockIdx.x * 4096 + (size_t)cn * 64 + l4 * 4;
    *(unsigned*)(pt2 +  0) = cvt_pk_bf16(C0[0],C0[1]);
    *(unsigned*)(pt2 +  2) = cvt_pk_bf16(C0[2],C0[3]);
    *(unsigned*)(pt2 + 16) = cvt_pk_bf16(C1[0],C1[1]);
    *(unsigned*)(pt2 + 18) = cvt_pk_bf16(C1[2],C1[3]);
    *(unsigned*)(pt2 + 32) = cvt_pk_bf16(C2[0],C2[1]);
    *(unsigned*)(pt2 + 34) = cvt_pk_bf16(C2[2],C2[3]);
    *(unsigned*)(pt2 + 48) = cvt_pk_bf16(C3[0],C3[1]);
    *(unsigned*)(pt2 + 50) = cvt_pk_bf16(C3[2],C3[3]);
    if (l4 == 0)
        ws[LBASE + blockIdx.x * 64 + cn] = logacc + (float)((double)nst * LOG64);
}
#endif // HAVE16

// ================= combine: alpha <- P_s alpha over segments =================
__global__ __launch_bounds__(64) void crf_combine2(
    const float* __restrict__ em, float* __restrict__ ws, int sshift)
{
    const int b = blockIdx.x, m = threadIdx.x;
    const int nseg = 1 << sshift;
    __shared__ float xs[TT];
    float alpha = __expf(em[(size_t)b * (SS * TT) + m]);   // alpha_0
    float logA = 0.f;
    for (int s = 0; s < nseg; ++s) {
        const int seg = b * nseg + s;
        const float Li = ws[LBASE + seg * 64 + m];         // per-column scale
        float Lmax = Li;
        for (int off = 1; off < 64; off <<= 1) Lmax = fmaxf(Lmax, __shfl_xor(Lmax, off));
        xs[m] = alpha * __expf(Li - Lmax);
        const uint16_t* Pp = (const uint16_t*)(ws + PBASE_F) + (size_t)seg * 4096;
        float y = 0.f;
#pragma unroll 8
        for (int i = 0; i < TT; ++i) {
            const float pv = __uint_as_float((unsigned)Pp[i * 64 + m] << 16);
            y = fmaf(pv, xs[i], y);
        }
        logA += Lmax;
        float mx = y;
        for (int off = 1; off < 64; off <<= 1) mx = fmaxf(mx, __shfl_xor(mx, off));
        alpha = y * __builtin_amdgcn_rcpf(mx);
        logA += __logf(mx);
    }
    float ssum = alpha;
    for (int off = 1; off < 64; off <<= 1) ssum += __shfl_xor(ssum, off);
    if (m == 0)
        ws[OUTB + b] = ws[GBASE + b] - (logA + __logf(ssum));   // gold - logZ
}

// ================= gold score =================
__global__ __launch_bounds__(256) void crf_gold_kernel(
    const float* __restrict__ em, const float* __restrict__ trans,
    const uint32_t* __restrict__ tw, float* __restrict__ gdst, int gstride)
{
    const int b = blockIdx.x, tid = threadIdx.x;
    uint32_t orv = 0;
    for (int k = 1; k < 32; k += 2) orv |= tw[k];
    const int is64 = (orv == 0) ? 1 : 0;
    const int    tbase = b * SS;
    const size_t ebase = (size_t)b * SS * TT;
    float s = 0.0f;
    for (int t = tid; t < SS; t += 256) {
        const int tg = ldtag(tw, tbase + t, is64);
        float v = em[ebase + (size_t)t * TT + tg];
        if (t > 0) {
            const int tp = ldtag(tw, tbase + t - 1, is64);
            v += trans[tp * TT + tg];
        }
        s += v;
    }
    for (int off = 1; off < 64; off <<= 1) s += __shfl_xor(s, off);
    __shared__ float sh[4];
    if ((tid & 63) == 0) sh[tid >> 6] = s;
    __syncthreads();
    if (tid == 0) gdst[b * gstride] = sh[0] + sh[1] + sh[2] + sh[3];
}

// ================= old path (R7, proven fallback) =================
__device__ __forceinline__ float qsum4(float v) {
    int a = __builtin_amdgcn_mov_dpp(__float_as_int(v), 0xB1, 0xF, 0xF, true);
    float v1 = v + __int_as_float(a);
    int b2 = __builtin_amdgcn_mov_dpp(__float_as_int(v1), 0x4E, 0xF, 0xF, true);
    return v1 + __int_as_float(b2);
}
#define LDS_BARRIER() asm volatile("s_waitcnt lgkmcnt(0)\n\ts_barrier" ::: "memory")

template <int DIR>
__device__ __forceinline__ void fb_run(const float* __restrict__ em,
                                       const float* __restrict__ trans,
                                       float* __restrict__ ws,
                                       float* __restrict__ qbuf,
                                       int b, int tid)
{
    const int l   = tid & 63;
    const int w   = tid >> 6;
    const int j   = (w << 4) | (l >> 2);
    const int sub = l & 3;
#define TRIDX(k) (DIR ? (j * 64 + (sub * 16 + (k))) : ((sub * 16 + (k)) * 64 + j))
#define ED(k) const float E##k = __expf(trans[TRIDX(k)]) * 0.015625f;
    ED(0) ED(1) ED(2) ED(3) ED(4) ED(5) ED(6) ED(7)
    ED(8) ED(9) ED(10) ED(11) ED(12) ED(13) ED(14) ED(15)
#undef ED
#undef TRIDX
    const size_t ebase  = (size_t)b * SS * TT;
    constexpr int nsteps = DIR ? (SS - M_SPLIT) : (M_SPLIT - 1);
    constexpr int estep  = DIR ? -TT : TT;
    constexpr int t0     = DIR ? (SS - 2) : 1;
    const float* ep = em + ebase + (size_t)t0 * TT + j;
    float p0 = ep[0];
    float p1 = ep[1 * estep];
    float p2 = ep[2 * estep];
    float p3 = ep[3 * estep];
    if (tid < TT) {
        const size_t it = DIR ? ((size_t)(SS - 1) * TT) : 0;
        qbuf[tid] = __expf(em[ebase + it + tid]);
    }
    LDS_BARRIER();
    float logsum = 0.0f;
    int cur = 0;
    for (int si = 0; si < nsteps; ++si) {
        const float e = p0;
        p0 = p1; p1 = p2; p2 = p3;
        p3 = ep[4 * estep];
        ep += estep;
        float* rb = qbuf + (cur << 6);
        float* wb = qbuf + ((cur ^ 1) << 6);
        const float4 q0 = *(const float4*)(rb + sub * 16 + 0);
        const float4 q1 = *(const float4*)(rb + sub * 16 + 4);
        const float4 q2 = *(const float4*)(rb + sub * 16 + 8);
        const float4 q3 = *(const float4*)(rb + sub * 16 + 12);
        float a0 = 0, a1 = 0, a2 = 0, a3 = 0;
        a0 = fmaf(q0.x, E0,  a0); a1 = fmaf(q0.y, E1,  a1);
        a2 = fmaf(q0.z, E2,  a2); a3 = fmaf(q0.w, E3,  a3);
        a0 = fmaf(q1.x, E4,  a0); a1 = fmaf(q1.y, E5,  a1);
        a2 = fmaf(q1.z, E6,  a2); a3 = fmaf(q1.w, E7,  a3);
        a0 = fmaf(q2.x, E8,  a0); a1 = fmaf(q2.y, E9,  a1);
        a2 = fmaf(q2.z, E10, a2); a3 = fmaf(q2.w, E11, a3);
        a0 = fmaf(q3.x, E12, a0); a1 = fmaf(q3.y, E13, a1);
        a2 = fmaf(q3.z, E14, a2); a3 = fmaf(q3.w, E15, a3);
        float dot = (a0 + a1) + (a2 + a3);
        dot = qsum4(dot);
        float fv = __expf(e);
        if (DIR && si == nsteps - 1) fv = 1.0f;
        float wval = dot * fv;
        if ((si & 63) == 63) {
            const float m = rb[0];
            wval *= __builtin_amdgcn_rcpf(m);
            if (tid == 0) logsum += __logf(m);
        }
        if (sub == 0) wb[j] = wval;
        LDS_BARRIER();
        cur ^= 1;
    }
    const float* fin = qbuf + (cur << 6);
    float* wsb = ws + (size_t)b * WS_STRIDE;
    if (tid < TT) wsb[(DIR ? TT : 0) + tid] = fin[tid];
    if (tid == 0) wsb[DIR ? 129 : 128] = (float)((double)nsteps * LOG64) + logsum;
}

__global__ __launch_bounds__(256) void crf_fb_kernel(
    const float* __restrict__ em, const float* __restrict__ trans,
    float* __restrict__ ws)
{
    const int b   = blockIdx.x & (BB - 1);
    const int dir = blockIdx.x >> 8;
    __shared__ __align__(16) float qbuf[2 * TT];
    if (dir == 0) fb_run<0>(em, trans, ws, qbuf, b, threadIdx.x);
    else          fb_run<1>(em, trans, ws, qbuf, b, threadIdx.x);
}

__global__ __launch_bounds__(64) void crf_combine_kernel(
    const float* __restrict__ ws, float* __restrict__ outb)
{
    const int b = blockIdx.x, lane = threadIdx.x;
    const float* wsb = ws + (size_t)b * WS_STRIDE;
    float p = wsb[lane] * wsb[64 + lane];
    for (int off = 1; off < 64; off <<= 1) p += __shfl_xor(p, off);
    if (lane == 0) {
        const float logz = wsb[128] + wsb[129] + __logf(p);
        outb[b] = wsb[130] - logz;
    }
}

__global__ __launch_bounds__(256) void crf_final_kernel(
    const float* __restrict__ vals, float* __restrict__ out)
{
    const int l = threadIdx.x;
    float v = vals[l];
    for (int off = 1; off < 64; off <<= 1) v += __shfl_xor(v, off);
    __shared__ float sh[4];
    if ((l & 63) == 0) sh[l >> 6] = v;
    __syncthreads();
    if (l == 0) out[0] = -(sh[0] + sh[1] + sh[2] + sh[3]) * (1.0f / BB);
}

extern "C" void kernel_launch(void* const* d_in, const int* in_sizes, int n_in,
                              void* d_out, int out_size, void* d_ws, size_t ws_size,
                              hipStream_t stream) {
    const float*    em    = (const float*)d_in[0];
    const float*    trans = (const float*)d_in[1];
    const uint32_t* tw    = (const uint32_t*)d_in[2];
    float* ws = (float*)d_ws;

    // adaptive segment count by workspace: 8 -> ~17.3MB, 4 -> ~8.9MB, 2 -> ~4.7MB
    int sshift = 0;
    const size_t hdr = (size_t)PBASE_F * 4;
    if      (ws_size >= hdr + (((size_t)BB << 3) * 4096 * 2)) sshift = 3;
    else if (ws_size >= hdr + (((size_t)BB << 2) * 4096 * 2)) sshift = 2;
    else if (ws_size >= hdr + (((size_t)BB << 1) * 4096 * 2)) sshift = 1;

#if HAVE32
    if (sshift) {
        dim3 g(BB << sshift, 2);
        crf_seg32_kernel<<<g, 64, 0, stream>>>(em, trans, ws, sshift);
        crf_gold_kernel<<<BB, 256, 0, stream>>>(em, trans, tw, ws + GBASE, 1);
        crf_combine2<<<BB, 64, 0, stream>>>(em, ws, sshift);
        crf_final_kernel<<<1, 256, 0, stream>>>(ws + OUTB, (float*)d_out);
        return;
    }
#elif HAVE16
    if (sshift) {
        dim3 g(BB << sshift, 4);
        crf_seg_kernel<<<g, 64, 0, stream>>>(em, trans, ws, sshift);
        crf_gold_kernel<<<BB, 256, 0, stream>>>(em, trans, tw, ws + GBASE, 1);
        crf_combine2<<<BB, 64, 0, stream>>>(em, ws, sshift);
        crf_final_kernel<<<1, 256, 0, stream>>>(ws + OUTB, (float*)d_out);
        return;
    }
#endif

    // fallback: proven R7 path
    float* outb = ws + (size_t)BB * WS_STRIDE;
    crf_fb_kernel<<<2 * BB, 256, 0, stream>>>(em, trans, ws);
    crf_gold_kernel<<<BB, 256, 0, stream>>>(em, trans, tw, ws + 130, WS_STRIDE);
    crf_combine_kernel<<<BB, 64, 0, stream>>>(ws, outb);
    crf_final_kernel<<<1, 256, 0, stream>>>(outb, (float*)d_out);
}